// Round 6
// baseline (299.759 us; speedup 1.0000x reference)
//
#include <hip/hip_runtime.h>
#include <math.h>

#define THREADS 256   // 4 threads per token
#define TPB 64        // tokens per block
#define NEXP 256
#define EPS_S 2.0e-6f // single-score margins (f32 score err <= ~4e-7, 2.5x safety)
#define EPS_G 4.0e-6f // group-sum margins

// ---- fast f32 sigmoid: hw v_exp_f32 + fast divide ----
__device__ __forceinline__ float fsigmoid(float x) {
    float e = __expf(-x);
    return __fdividef(1.0f, 1.0f + e);
}

// ---- cheap near-exact f64 sigmoid (rare paths only): Taylor exp + NR division ----
__device__ __forceinline__ double dsigmoid(float xf) {
    xf = fminf(fmaxf(xf, -500.0f), 500.0f);
    double x = (double)xf;
    double t = x * -1.4426950408889634074;           // -x*log2(e)
    double n = floor(t + 0.5);
    int ni = (int)n;
    double u = (t - n) * 0.69314718055994530942;
    double pp = 2.08767569878680990e-9;
    pp = fma(pp, u, 2.50521083854417188e-8);
    pp = fma(pp, u, 2.75573192239858907e-7);
    pp = fma(pp, u, 2.75573192239858883e-6);
    pp = fma(pp, u, 2.48015873015873016e-5);
    pp = fma(pp, u, 1.98412698412698413e-4);
    pp = fma(pp, u, 1.38888888888888889e-3);
    pp = fma(pp, u, 8.33333333333333333e-3);
    pp = fma(pp, u, 4.16666666666666667e-2);
    pp = fma(pp, u, 1.66666666666666667e-1);
    pp = fma(pp, u, 0.5);
    pp = fma(pp, u, 1.0);
    pp = fma(pp, u, 1.0);
    double sc = __longlong_as_double((long long)(1023 + ni) << 52);
    double e = pp * sc;                              // exp(-x)
    double w = 1.0 + e;
    double y = (double)__fdividef(1.0f, (float)w);
    y = fma(y, fma(-w, y, 1.0), y);
    y = fma(y, fma(-w, y, 1.0), y);
    return y;
}

// 9-deep sorted-descending insert (named scalars m0..m8 / n0..n8), gated on m8.
// strict > : existing (earlier/lower-id) entry wins ties.
#define MINS(cc, ee) do {                                                \
    float _c=(cc); int _e=(ee);                                          \
    if (_c > m8) {                                                       \
        bool _b0=_c>m0,_b1=_c>m1,_b2=_c>m2,_b3=_c>m3,_b4=_c>m4,          \
             _b5=_c>m5,_b6=_c>m6,_b7=_c>m7;                              \
        m8=_b7?m7:_c;           n8=_b7?n7:_e;                            \
        m7=_b6?m6:(_b7?_c:m7);  n7=_b6?n6:(_b7?_e:n7);                   \
        m6=_b5?m5:(_b6?_c:m6);  n6=_b5?n5:(_b6?_e:n6);                   \
        m5=_b4?m4:(_b5?_c:m5);  n5=_b4?n4:(_b5?_e:n5);                   \
        m4=_b3?m3:(_b4?_c:m4);  n4=_b3?n3:(_b4?_e:n4);                   \
        m3=_b2?m2:(_b3?_c:m3);  n3=_b2?n2:(_b3?_e:n3);                   \
        m2=_b1?m1:(_b2?_c:m2);  n2=_b1?n1:(_b2?_e:n2);                   \
        m1=_b0?m0:(_b1?_c:m1);  n1=_b0?n0:(_b1?_e:n1);                   \
        m0=_b0?_c:m0;           n0=_b0?_e:n0;                            \
    } } while (0)

// f64 8-deep sorted insert (cold path)
#define DINS(cc, ee) do {                                                \
    double _d=(cc); int _e=(ee);                                         \
    if (_d > s7) {                                                       \
        bool _b0=_d>s0,_b1=_d>s1,_b2=_d>s2,_b3=_d>s3,_b4=_d>s4,          \
             _b5=_d>s5,_b6=_d>s6;                                        \
        s7=_b6?s6:_d;           c7=_b6?c6:_e;                            \
        s6=_b5?s5:(_b6?_d:s6);  c6=_b5?c5:(_b6?_e:c6);                   \
        s5=_b4?s4:(_b5?_d:s5);  c5=_b4?c4:(_b5?_e:c5);                   \
        s4=_b3?s3:(_b4?_d:s4);  c4=_b3?c3:(_b4?_e:c4);                   \
        s3=_b2?s2:(_b3?_d:s3);  c3=_b2?c2:(_b3?_e:c3);                   \
        s2=_b1?s1:(_b2?_d:s2);  c2=_b1?c1:(_b2?_e:c2);                   \
        s1=_b0?s0:(_b1?_d:s1);  c1=_b0?c0:(_b1?_e:c1);                   \
        s0=_b0?_d:s0;           c0=_b0?_e:c0;                            \
    } } while (0)

// exchange the 9-deep list with xor-partner at distance d and merge
#define XMERGE(d) do {                                                   \
    float q0=__shfl_xor(m0,d,64), q1=__shfl_xor(m1,d,64),                \
          q2=__shfl_xor(m2,d,64), q3=__shfl_xor(m3,d,64),                \
          q4=__shfl_xor(m4,d,64), q5=__shfl_xor(m5,d,64),                \
          q6=__shfl_xor(m6,d,64), q7=__shfl_xor(m7,d,64),                \
          q8=__shfl_xor(m8,d,64);                                        \
    int   r0=__shfl_xor(n0,d,64), r1=__shfl_xor(n1,d,64),                \
          r2=__shfl_xor(n2,d,64), r3=__shfl_xor(n3,d,64),                \
          r4=__shfl_xor(n4,d,64), r5=__shfl_xor(n5,d,64),                \
          r6=__shfl_xor(n6,d,64), r7=__shfl_xor(n7,d,64),                \
          r8=__shfl_xor(n8,d,64);                                        \
    MINS(q0,r0); MINS(q1,r1); MINS(q2,r2); MINS(q3,r3); MINS(q4,r4);     \
    MINS(q5,r5); MINS(q6,r6); MINS(q7,r7); MINS(q8,r8);                  \
} while (0)

__global__ __launch_bounds__(THREADS, 4)
void noauxtc_router_kernel(const float* __restrict__ logits,
                           const float* __restrict__ bias,
                           float* __restrict__ out,   // [T*8] weights, [T*8] ids-as-f32
                           int T)
{
    __shared__ float bias_sh[NEXP + 4];   // padded: idx e + (e>>6) -> h-classes hit distinct banks

    const int tid = threadIdx.x;
    const int h   = tid & 3;              // owns groups 2h, 2h+1 (experts 64h..64h+63)
    const int p   = tid >> 2;             // token-in-block
    const int tok0  = blockIdx.x * TPB;
    const int token = tok0 + p;

    bias_sh[tid + (tid >> 6)] = bias[tid];     // THREADS == NEXP
    __syncthreads();                           // only barrier in the kernel

    const float4* row4 = (const float4*)logits + (size_t)token * 64 + h * 16;

    // ---------------- pass A: own 2 group scores (top-2 sum), direct global->reg ----------------
    float gsE, gsO;
    {
        float a1 = -3e38f, a2 = -3e38f;
        #pragma unroll
        for (int q = 0; q < 8; ++q) {
            float4 x = row4[q];
            int ro = h * 65 + q * 4;                 // padded idx of expert 64h+4q
            float c;
            c = fsigmoid(x.x) + bias_sh[ro+0]; a2 = fmaxf(a2, fminf(a1,c)); a1 = fmaxf(a1,c);
            c = fsigmoid(x.y) + bias_sh[ro+1]; a2 = fmaxf(a2, fminf(a1,c)); a1 = fmaxf(a1,c);
            c = fsigmoid(x.z) + bias_sh[ro+2]; a2 = fmaxf(a2, fminf(a1,c)); a1 = fmaxf(a1,c);
            c = fsigmoid(x.w) + bias_sh[ro+3]; a2 = fmaxf(a2, fminf(a1,c)); a1 = fmaxf(a1,c);
        }
        gsE = a1 + a2;
    }
    {
        float a1 = -3e38f, a2 = -3e38f;
        #pragma unroll
        for (int q = 0; q < 8; ++q) {
            float4 x = row4[8 + q];
            int ro = h * 65 + 32 + q * 4;
            float c;
            c = fsigmoid(x.x) + bias_sh[ro+0]; a2 = fmaxf(a2, fminf(a1,c)); a1 = fmaxf(a1,c);
            c = fsigmoid(x.y) + bias_sh[ro+1]; a2 = fmaxf(a2, fminf(a1,c)); a1 = fmaxf(a1,c);
            c = fsigmoid(x.z) + bias_sh[ro+2]; a2 = fmaxf(a2, fminf(a1,c)); a1 = fmaxf(a1,c);
            c = fsigmoid(x.w) + bias_sh[ro+3]; a2 = fmaxf(a2, fminf(a1,c)); a1 = fmaxf(a1,c);
        }
        gsO = a1 + a2;
    }

    // ---------------- distribute all 8 group scores via xor shuffles ----------------
    float xe1 = __shfl_xor(gsE,1,64), xo1 = __shfl_xor(gsO,1,64);
    float xe2 = __shfl_xor(gsE,2,64), xo2 = __shfl_xor(gsO,2,64);
    float xe3 = __shfl_xor(gsE,3,64), xo3 = __shfl_xor(gsO,3,64);
    float gsv[8];
    #pragma unroll
    for (int b = 0; b < 4; ++b) {        // group pair 2b,2b+1 lives on lane with h==b
        int d = h ^ b;
        gsv[2*b]   = (d==0) ? gsE : (d==1) ? xe1 : (d==2) ? xe2 : xe3;
        gsv[2*b+1] = (d==0) ? gsO : (d==1) ? xo1 : (d==2) ? xo2 : xo3;
    }

    // ---------------- top-4 groups (rank count, lower idx wins) + margin ----------------
    int selmask = 0; float val4 = 0.f, val5 = 0.f;
    #pragma unroll
    for (int a = 0; a < 8; ++a) {
        int rk = 0;
        #pragma unroll
        for (int b = 0; b < 8; ++b) {
            if (b == a) continue;
            bool beat = (b < a) ? (gsv[b] >= gsv[a]) : (gsv[b] > gsv[a]);
            rk += beat ? 1 : 0;
        }
        selmask |= (rk < 4) ? (1 << a) : 0;
        val4 = (rk == 3) ? gsv[a] : val4;
        val5 = (rk == 4) ? gsv[a] : val5;
    }

    // ---- flagA: ambiguous 4th vs 5th group -> f64 recompute of boundary band (cold) ----
    if (__builtin_expect(val4 - val5 < EPS_G, 0)) {
        double gd[8];
        #pragma unroll 1
        for (int a = 0; a < 8; ++a) {
            float gf = gsv[a];
            if (gf >= val5 - EPS_G && gf <= val4 + EPS_G) {
                double a1 = -1e300, a2 = -1e300;
                const float* rowp = logits + (size_t)token * 256 + a * 32;
                for (int k = 0; k < 32; ++k) {
                    int e = a * 32 + k;
                    double c = dsigmoid(rowp[k]) + (double)bias_sh[e + (e >> 6)];
                    a2 = fmax(a2, fmin(a1, c)); a1 = fmax(a1, c);
                }
                gd[a] = a1 + a2;
            } else gd[a] = (double)gf;
        }
        int sm = 0;
        #pragma unroll
        for (int a = 0; a < 8; ++a) {
            int rk = 0;
            #pragma unroll
            for (int b = 0; b < 8; ++b) {
                if (b == a) continue;
                bool beat = (b < a) ? (gd[b] >= gd[a]) : (gd[b] > gd[a]);
                rk += beat ? 1 : 0;
            }
            sm |= (rk < 4) ? (1 << a) : 0;
        }
        selmask = sm;
    }

    // force the two-pass structure: compiler must NOT keep pass-A loads alive in 64 regs
    asm volatile("" ::: "memory");

    // ---------------- pass B: top-9 over own selected groups (L1/L2/L3-hot re-read) ----------------
    float m0=-3e38f,m1=-3e38f,m2=-3e38f,m3=-3e38f,m4=-3e38f,
          m5=-3e38f,m6=-3e38f,m7=-3e38f,m8=-3e38f;
    int n0=0,n1=0,n2=0,n3=0,n4=0,n5=0,n6=0,n7=0,n8=0;

    #pragma unroll
    for (int sub = 0; sub < 2; ++sub) {
        if ((selmask >> (2*h + sub)) & 1) {
            #pragma unroll
            for (int q = 0; q < 8; ++q) {
                float4 x = row4[sub*8 + q];
                int eb = h*64 + sub*32 + q*4;
                int ro = eb + h;                   // padded bias idx
                float c;
                c = fsigmoid(x.x) + bias_sh[ro+0]; MINS(c, eb+0);
                c = fsigmoid(x.y) + bias_sh[ro+1]; MINS(c, eb+1);
                c = fsigmoid(x.z) + bias_sh[ro+2]; MINS(c, eb+2);
                c = fsigmoid(x.w) + bias_sh[ro+3]; MINS(c, eb+3);
            }
        }
    }

    // ---------------- butterfly merge: h0<-h1, then h0<-(h2 merged h3) ----------------
    // incoming ids always > own ids on the h==0 result lane -> strict > is exact tie-break
    XMERGE(1);
    XMERGE(2);

    // ---------------- fast-path result + flagB (h==0 lanes own the token) ----------------
    float w0 = m0 - bias_sh[n0+(n0>>6)], w1 = m1 - bias_sh[n1+(n1>>6)],
          w2 = m2 - bias_sh[n2+(n2>>6)], w3 = m3 - bias_sh[n3+(n3>>6)],
          w4 = m4 - bias_sh[n4+(n4>>6)], w5 = m5 - bias_sh[n5+(n5>>6)],
          w6 = m6 - bias_sh[n6+(n6>>6)], w7 = m7 - bias_sh[n7+(n7>>6)];
    int o0=n0,o1=n1,o2=n2,o3=n3,o4=n4,o5=n5,o6=n6,o7=n7;

    bool flagB = (h == 0) &&
                 (((m0-m1)<EPS_S)|((m1-m2)<EPS_S)|((m2-m3)<EPS_S)|((m3-m4)<EPS_S)|
                  ((m4-m5)<EPS_S)|((m5-m6)<EPS_S)|((m6-m7)<EPS_S)|((m7-m8)<EPS_S));
    if (__builtin_expect(flagB, 0)) {
        // f64 re-resolve of the 9 f32-top candidates (true top-8 within them)
        double s0=-1e300,s1=-1e300,s2=-1e300,s3=-1e300,
               s4=-1e300,s5=-1e300,s6=-1e300,s7=-1e300;
        int c0=0,c1=0,c2=0,c3=0,c4=0,c5=0,c6=0,c7=0;
        const float* row = logits + (size_t)token * 256;
        double cs;
        cs = dsigmoid(row[n0]) + (double)bias_sh[n0+(n0>>6)]; DINS(cs, n0);
        cs = dsigmoid(row[n1]) + (double)bias_sh[n1+(n1>>6)]; DINS(cs, n1);
        cs = dsigmoid(row[n2]) + (double)bias_sh[n2+(n2>>6)]; DINS(cs, n2);
        cs = dsigmoid(row[n3]) + (double)bias_sh[n3+(n3>>6)]; DINS(cs, n3);
        cs = dsigmoid(row[n4]) + (double)bias_sh[n4+(n4>>6)]; DINS(cs, n4);
        cs = dsigmoid(row[n5]) + (double)bias_sh[n5+(n5>>6)]; DINS(cs, n5);
        cs = dsigmoid(row[n6]) + (double)bias_sh[n6+(n6>>6)]; DINS(cs, n6);
        cs = dsigmoid(row[n7]) + (double)bias_sh[n7+(n7>>6)]; DINS(cs, n7);
        cs = dsigmoid(row[n8]) + (double)bias_sh[n8+(n8>>6)]; DINS(cs, n8);
        // DINS strict > on insertion order n0..n8; n-list is value-sorted with
        // lower-id-first on equals, so equal f64 values keep lower id first (np semantics)
        w0=(float)(s0-(double)bias_sh[c0+(c0>>6)]); o0=c0;
        w1=(float)(s1-(double)bias_sh[c1+(c1>>6)]); o1=c1;
        w2=(float)(s2-(double)bias_sh[c2+(c2>>6)]); o2=c2;
        w3=(float)(s3-(double)bias_sh[c3+(c3>>6)]); o3=c3;
        w4=(float)(s4-(double)bias_sh[c4+(c4>>6)]); o4=c4;
        w5=(float)(s5-(double)bias_sh[c5+(c5>>6)]); o5=c5;
        w6=(float)(s6-(double)bias_sh[c6+(c6>>6)]); o6=c6;
        w7=(float)(s7-(double)bias_sh[c7+(c7>>6)]); o7=c7;
    }

    // ---------------- epilogue ----------------
    if (h == 0) {
        float sum = ((w0+w1)+(w2+w3)) + ((w4+w5)+(w6+w7));
        float scl = 2.5f / (sum + 1e-20f);
        float4 oa, ob;
        oa.x=w0*scl; oa.y=w1*scl; oa.z=w2*scl; oa.w=w3*scl;
        ob.x=w4*scl; ob.y=w5*scl; ob.z=w6*scl; ob.w=w7*scl;
        *(float4*)(out + (size_t)token*8)     = oa;
        *(float4*)(out + (size_t)token*8 + 4) = ob;
        float* oid = out + (size_t)T*8;
        float4 ia, ib;
        ia.x=(float)o0; ia.y=(float)o1; ia.z=(float)o2; ia.w=(float)o3;
        ib.x=(float)o4; ib.y=(float)o5; ib.z=(float)o6; ib.w=(float)o7;
        *(float4*)(oid + (size_t)token*8)     = ia;
        *(float4*)(oid + (size_t)token*8 + 4) = ib;
    }
}

extern "C" void kernel_launch(void* const* d_in, const int* in_sizes, int n_in,
                              void* d_out, int out_size, void* d_ws, size_t ws_size,
                              hipStream_t stream) {
    const float* logits = (const float*)d_in[0];
    const float* bias   = (const float*)d_in[1];
    float* out = (float*)d_out;
    int T = in_sizes[0] / NEXP;        // 131072
    int nblocks = T / TPB;             // 2048
    noauxtc_router_kernel<<<nblocks, THREADS, 0, stream>>>(logits, bias, out, T);
}

// Round 7
// 233.024 us; speedup vs baseline: 1.2864x; 1.2864x over previous
//
#include <hip/hip_runtime.h>
#include <math.h>

#define THREADS 256   // 8 threads per token; thread = one expert group
#define TPB 32        // tokens per block
#define NEXP 256
#define EPS_S 2.0e-6f // single-score margins (f32 score err <= ~4e-7, 5x safety)
#define EPS_G 4.0e-6f // group-sum margins

// ---- fast f32 sigmoid: hw v_exp_f32 + fast divide ----
__device__ __forceinline__ float fsigmoid(float x) {
    float e = __expf(-x);
    return __fdividef(1.0f, 1.0f + e);
}

// ---- cheap near-exact f64 sigmoid (rare paths only): Taylor exp + NR division ----
__device__ __forceinline__ double dsigmoid(float xf) {
    xf = fminf(fmaxf(xf, -500.0f), 500.0f);
    double x = (double)xf;
    double t = x * -1.4426950408889634074;           // -x*log2(e)
    double n = floor(t + 0.5);
    int ni = (int)n;
    double u = (t - n) * 0.69314718055994530942;
    double pp = 2.08767569878680990e-9;
    pp = fma(pp, u, 2.50521083854417188e-8);
    pp = fma(pp, u, 2.75573192239858907e-7);
    pp = fma(pp, u, 2.75573192239858883e-6);
    pp = fma(pp, u, 2.48015873015873016e-5);
    pp = fma(pp, u, 1.98412698412698413e-4);
    pp = fma(pp, u, 1.38888888888888889e-3);
    pp = fma(pp, u, 8.33333333333333333e-3);
    pp = fma(pp, u, 4.16666666666666667e-2);
    pp = fma(pp, u, 1.66666666666666667e-1);
    pp = fma(pp, u, 0.5);
    pp = fma(pp, u, 1.0);
    pp = fma(pp, u, 1.0);
    double sc = __longlong_as_double((long long)(1023 + ni) << 52);
    double e = pp * sc;                              // exp(-x)
    double w = 1.0 + e;
    double y = (double)__fdividef(1.0f, (float)w);
    y = fma(y, fma(-w, y, 1.0), y);
    y = fma(y, fma(-w, y, 1.0), y);
    return y;
}

// 9-deep sorted-descending insert (named scalars m0..m8 / n0..n8), gated on m8.
// strict > : existing (earlier/lower-id) entry wins ties.
#define MINS(cc, ee) do {                                                \
    float _c=(cc); int _e=(ee);                                          \
    if (_c > m8) {                                                       \
        bool _b0=_c>m0,_b1=_c>m1,_b2=_c>m2,_b3=_c>m3,_b4=_c>m4,          \
             _b5=_c>m5,_b6=_c>m6,_b7=_c>m7;                              \
        m8=_b7?m7:_c;           n8=_b7?n7:_e;                            \
        m7=_b6?m6:(_b7?_c:m7);  n7=_b6?n6:(_b7?_e:n7);                   \
        m6=_b5?m5:(_b6?_c:m6);  n6=_b5?n5:(_b6?_e:n6);                   \
        m5=_b4?m4:(_b5?_c:m5);  n5=_b4?n4:(_b5?_e:n5);                   \
        m4=_b3?m3:(_b4?_c:m4);  n4=_b3?n3:(_b4?_e:n4);                   \
        m3=_b2?m2:(_b3?_c:m3);  n3=_b2?n2:(_b3?_e:n3);                   \
        m2=_b1?m1:(_b2?_c:m2);  n2=_b1?n1:(_b2?_e:n2);                   \
        m1=_b0?m0:(_b1?_c:m1);  n1=_b0?n0:(_b1?_e:n1);                   \
        m0=_b0?_c:m0;           n0=_b0?_e:n0;                            \
    } } while (0)

// f64 8-deep sorted insert (cold path)
#define DINS(cc, ee) do {                                                \
    double _d=(cc); int _e=(ee);                                         \
    if (_d > s7) {                                                       \
        bool _b0=_d>s0,_b1=_d>s1,_b2=_d>s2,_b3=_d>s3,_b4=_d>s4,          \
             _b5=_d>s5,_b6=_d>s6;                                        \
        s7=_b6?s6:_d;           c7=_b6?c6:_e;                            \
        s6=_b5?s5:(_b6?_d:s6);  c6=_b5?c5:(_b6?_e:c6);                   \
        s5=_b4?s4:(_b5?_d:s5);  c5=_b4?c4:(_b5?_e:c5);                   \
        s4=_b3?s3:(_b4?_d:s4);  c4=_b3?c3:(_b4?_e:c4);                   \
        s3=_b2?s2:(_b3?_d:s3);  c3=_b2?c2:(_b3?_e:c3);                   \
        s2=_b1?s1:(_b2?_d:s2);  c2=_b1?c1:(_b2?_e:c2);                   \
        s1=_b0?s0:(_b1?_d:s1);  c1=_b0?c0:(_b1?_e:c1);                   \
        s0=_b0?_d:s0;           c0=_b0?_e:c0;                            \
    } } while (0)

// exchange the 9-deep list with xor-partner at distance d and merge
#define XMERGE(d) do {                                                   \
    float q0=__shfl_xor(m0,d,64), q1=__shfl_xor(m1,d,64),                \
          q2=__shfl_xor(m2,d,64), q3=__shfl_xor(m3,d,64),                \
          q4=__shfl_xor(m4,d,64), q5=__shfl_xor(m5,d,64),                \
          q6=__shfl_xor(m6,d,64), q7=__shfl_xor(m7,d,64),                \
          q8=__shfl_xor(m8,d,64);                                        \
    int   r0=__shfl_xor(n0,d,64), r1=__shfl_xor(n1,d,64),                \
          r2=__shfl_xor(n2,d,64), r3=__shfl_xor(n3,d,64),                \
          r4=__shfl_xor(n4,d,64), r5=__shfl_xor(n5,d,64),                \
          r6=__shfl_xor(n6,d,64), r7=__shfl_xor(n7,d,64),                \
          r8=__shfl_xor(n8,d,64);                                        \
    MINS(q0,r0); MINS(q1,r1); MINS(q2,r2); MINS(q3,r3); MINS(q4,r4);     \
    MINS(q5,r5); MINS(q6,r6); MINS(q7,r7); MINS(q8,r8);                  \
} while (0)

__global__ __launch_bounds__(THREADS, 4)
void noauxtc_router_kernel(const float* __restrict__ logits,
                           const float* __restrict__ bias,
                           float* __restrict__ out,   // [T*8] weights, [T*8] ids-as-f32
                           int T)
{
    // 32 tokens x 64 float4, xor-swizzled: element (t, c) at tile4[t*64 + (c ^ (t&7))]
    // write side: full-row b128 permuted writes -> conflict-free
    // read side: thread (p,h) q: col h*8+q, xor p&7 spreads 8 p-classes over 32 banks
    __shared__ float4 tile4[TPB * 64];                 // 32 KiB
    __shared__ __align__(16) float bias_sh[NEXP];      // 1 KiB

    const int tid = threadIdx.x;
    const int h   = tid & 7;              // owned group (experts 32h..32h+31)
    const int p   = tid >> 3;             // token-in-block
    const int pm  = p & 7;                // read-swizzle key
    const int tok0  = blockIdx.x * TPB;
    const int token = tok0 + p;

    bias_sh[tid] = bias[tid];             // THREADS == NEXP

    // ---------------- stage: 2048 float4, 8/thread, 4KB contiguous per instruction ----------------
    const float4* lg4 = (const float4*)logits;
    float4 st[8];
    #pragma unroll
    for (int k = 0; k < 8; ++k)
        st[k] = lg4[(size_t)tok0 * 64 + k * 256 + tid];
    #pragma unroll
    for (int k = 0; k < 8; ++k) {
        int flat = k * 256 + tid;
        int t = flat >> 6, c = flat & 63;
        tile4[t * 64 + (c ^ (t & 7))] = st[k];
    }
    __syncthreads();   // tile + bias ready (only barrier)

    const float4* bias4 = (const float4*)bias_sh;

    // ---------------- single scan: own group's top-9 (corrected scores) ----------------
    float m0=-3e38f,m1=-3e38f,m2=-3e38f,m3=-3e38f,m4=-3e38f,
          m5=-3e38f,m6=-3e38f,m7=-3e38f,m8=-3e38f;
    int n0=0,n1=0,n2=0,n3=0,n4=0,n5=0,n6=0,n7=0,n8=0;
    #pragma unroll
    for (int q = 0; q < 8; ++q) {
        float4 x  = tile4[p * 64 + ((h * 8 + q) ^ pm)];
        float4 bb = bias4[h * 8 + q];           // 8 addrs on 4 banks: 2-way = free
        int eb = h * 32 + q * 4;
        float c;
        c = fsigmoid(x.x) + bb.x; MINS(c, eb+0);
        c = fsigmoid(x.y) + bb.y; MINS(c, eb+1);
        c = fsigmoid(x.z) + bb.z; MINS(c, eb+2);
        c = fsigmoid(x.w) + bb.w; MINS(c, eb+3);
    }
    float gs = m0 + m1;                         // group score = top-2 sum (free, sorted list)

    // ---------------- all 8 group scores via bpermute gather ----------------
    const int base = (tid & 63) & 56;           // first lane of this token's octet
    float gsv[8];
    #pragma unroll
    for (int g = 0; g < 8; ++g) gsv[g] = __shfl(gs, base + g, 64);

    // ---------------- top-4 groups (rank count, lower idx wins) + margin ----------------
    int selmask = 0; float val4 = 0.f, val5 = 0.f;
    #pragma unroll
    for (int a = 0; a < 8; ++a) {
        int rk = 0;
        #pragma unroll
        for (int b = 0; b < 8; ++b) {
            if (b == a) continue;
            bool beat = (b < a) ? (gsv[b] >= gsv[a]) : (gsv[b] > gsv[a]);
            rk += beat ? 1 : 0;
        }
        selmask |= (rk < 4) ? (1 << a) : 0;
        val4 = (rk == 3) ? gsv[a] : val4;
        val5 = (rk == 4) ? gsv[a] : val5;
    }

    // ---- flagA: ambiguous 4th vs 5th group -> f64 re-rank of boundary band (cold, from LDS) ----
    if (__builtin_expect(val4 - val5 < EPS_G, 0)) {
        double gd[8];
        #pragma unroll 1
        for (int a = 0; a < 8; ++a) {
            float gf = gsv[a];
            if (gf >= val5 - EPS_G && gf <= val4 + EPS_G) {
                double a1 = -1e300, a2 = -1e300;
                for (int k = 0; k < 32; ++k) {
                    int e = a * 32 + k;
                    const float* tf = (const float*)(tile4 + p * 64 + ((e >> 2) ^ pm));
                    double c = dsigmoid(tf[e & 3]) + (double)bias_sh[e];
                    a2 = fmax(a2, fmin(a1, c)); a1 = fmax(a1, c);
                }
                gd[a] = a1 + a2;
            } else gd[a] = (double)gf;
        }
        int sm = 0;
        #pragma unroll
        for (int a = 0; a < 8; ++a) {
            int rk = 0;
            #pragma unroll
            for (int b = 0; b < 8; ++b) {
                if (b == a) continue;
                bool beat = (b < a) ? (gd[b] >= gd[a]) : (gd[b] > gd[a]);
                rk += beat ? 1 : 0;
            }
            sm |= (rk < 4) ? (1 << a) : 0;
        }
        selmask = sm;
    }

    // ---------------- mask unselected groups' lists, butterfly merge (xor 1,2,4) ----------------
    {
        bool sel = (selmask >> h) & 1;          // >=4*9 finite candidates survive -> -inf never wins
        m0 = sel ? m0 : -3e38f; m1 = sel ? m1 : -3e38f; m2 = sel ? m2 : -3e38f;
        m3 = sel ? m3 : -3e38f; m4 = sel ? m4 : -3e38f; m5 = sel ? m5 : -3e38f;
        m6 = sel ? m6 : -3e38f; m7 = sel ? m7 : -3e38f; m8 = sel ? m8 : -3e38f;
    }
    // on the h==0 result lane every consumed list comes from a higher group
    // (higher expert ids), so strict-> tie-break is exact down the whole chain
    XMERGE(1);
    XMERGE(2);
    XMERGE(4);

    // ---------------- fast-path result + flagB (h==0 lanes own the token) ----------------
    float w0 = m0 - bias_sh[n0], w1 = m1 - bias_sh[n1], w2 = m2 - bias_sh[n2],
          w3 = m3 - bias_sh[n3], w4 = m4 - bias_sh[n4], w5 = m5 - bias_sh[n5],
          w6 = m6 - bias_sh[n6], w7 = m7 - bias_sh[n7];
    int o0=n0,o1=n1,o2=n2,o3=n3,o4=n4,o5=n5,o6=n6,o7=n7;

    bool flagB = (h == 0) &&
                 (((m0-m1)<EPS_S)|((m1-m2)<EPS_S)|((m2-m3)<EPS_S)|((m3-m4)<EPS_S)|
                  ((m4-m5)<EPS_S)|((m5-m6)<EPS_S)|((m6-m7)<EPS_S)|((m7-m8)<EPS_S));
    if (__builtin_expect(flagB, 0)) {
        // f64 re-resolve of the 9 f32-top candidates (true top-8 within them); logits from LDS
        double s0=-1e300,s1=-1e300,s2=-1e300,s3=-1e300,
               s4=-1e300,s5=-1e300,s6=-1e300,s7=-1e300;
        int c0=0,c1=0,c2=0,c3=0,c4=0,c5=0,c6=0,c7=0;
        int ci[9] = {n0,n1,n2,n3,n4,n5,n6,n7,n8};
        #pragma unroll 1
        for (int k = 0; k < 9; ++k) {
            int e = ci[k];
            const float* tf = (const float*)(tile4 + p * 64 + ((e >> 2) ^ pm));
            double cs = dsigmoid(tf[e & 3]) + (double)bias_sh[e];
            DINS(cs, e);
        }
        // n-list is value-sorted, lower-id-first on equals; DINS strict > preserves that
        w0=(float)(s0-(double)bias_sh[c0]); o0=c0;
        w1=(float)(s1-(double)bias_sh[c1]); o1=c1;
        w2=(float)(s2-(double)bias_sh[c2]); o2=c2;
        w3=(float)(s3-(double)bias_sh[c3]); o3=c3;
        w4=(float)(s4-(double)bias_sh[c4]); o4=c4;
        w5=(float)(s5-(double)bias_sh[c5]); o5=c5;
        w6=(float)(s6-(double)bias_sh[c6]); o6=c6;
        w7=(float)(s7-(double)bias_sh[c7]); o7=c7;
    }

    // ---------------- epilogue ----------------
    if (h == 0) {
        float sum = ((w0+w1)+(w2+w3)) + ((w4+w5)+(w6+w7));
        float scl = 2.5f / (sum + 1e-20f);
        float4 oa, ob;
        oa.x=w0*scl; oa.y=w1*scl; oa.z=w2*scl; oa.w=w3*scl;
        ob.x=w4*scl; ob.y=w5*scl; ob.z=w6*scl; ob.w=w7*scl;
        *(float4*)(out + (size_t)token*8)     = oa;
        *(float4*)(out + (size_t)token*8 + 4) = ob;
        float* oid = out + (size_t)T*8;
        float4 ia, ib;
        ia.x=(float)o0; ia.y=(float)o1; ia.z=(float)o2; ia.w=(float)o3;
        ib.x=(float)o4; ib.y=(float)o5; ib.z=(float)o6; ib.w=(float)o7;
        *(float4*)(oid + (size_t)token*8)     = ia;
        *(float4*)(oid + (size_t)token*8 + 4) = ib;
    }
}

extern "C" void kernel_launch(void* const* d_in, const int* in_sizes, int n_in,
                              void* d_out, int out_size, void* d_ws, size_t ws_size,
                              hipStream_t stream) {
    const float* logits = (const float*)d_in[0];
    const float* bias   = (const float*)d_in[1];
    float* out = (float*)d_out;
    int T = in_sizes[0] / NEXP;        // 131072
    int nblocks = T / TPB;             // 4096
    noauxtc_router_kernel<<<nblocks, THREADS, 0, stream>>>(logits, bias, out, T);
}